// Round 10
// baseline (155.267 us; speedup 1.0000x reference)
//
#include <hip/hip_runtime.h>
#include <hip/hip_bf16.h>

#define HH 24
#define WW 8
#define HWSZ 192
#define CC 128
#define EPSV 1e-5f

#define M1LD 200   // M1 [24][M1LD] bf16
#define M2LD 28    // M2 [192][M2LD] bf16

typedef __attribute__((ext_vector_type(8))) short bf16x8;
typedef __attribute__((ext_vector_type(16))) float f32x16;

__device__ __forceinline__ float sigmoidf_(float x) { return 1.0f / (1.0f + expf(-x)); }

__device__ __forceinline__ unsigned short f2bf(float f) {
    unsigned int u = __float_as_uint(f);
    unsigned int r = (u + 0x7fffu + ((u >> 16) & 1u)) >> 16;
    return (unsigned short)r;
}
__device__ __forceinline__ float bf2f(unsigned short s) {
    return __uint_as_float((unsigned int)s << 16);
}

// ---------------- Kernel 1a: CBAM stats (phases 1-5), 64 blocks x 512 ----------------
__global__ __launch_bounds__(512) void cbam_stats(
    const float* __restrict__ prob, const float* __restrict__ gal,
    const float* __restrict__ se_w1, const float* __restrict__ se_w2,
    const float* __restrict__ sa_w, const float* __restrict__ sa_b,
    float* __restrict__ ca_out, float* __restrict__ sa_out)
{
    __shared__ float mxs[CC], avs[CC], hid[16], cas[CC];
    __shared__ float smx2[2 * HWSZ], sav2[2 * HWSZ];
    __shared__ float wbuf[2 * 49 * 49];

    int n = blockIdx.x;
    const float* x = (n < 32) ? prob + (size_t)n * CC * HWSZ : gal + (size_t)(n - 32) * CC * HWSZ;

    int tid = threadIdx.x, l = tid & 63, w = tid >> 6;

    for (int i = tid; i < 2 * 49 * 49; i += 512) wbuf[i] = sa_w[i];

    // phase 1: per-channel max/mean over 192 spatial (8 waves x 16 channels)
    for (int i = 0; i < 16; ++i) {
        int c = w * 16 + i;
        const float* row = x + c * HWSZ;
        float a = row[l], b = row[l + 64], d = row[l + 128];
        float mv = fmaxf(a, fmaxf(b, d));
        float sv = a + b + d;
        #pragma unroll
        for (int m = 1; m < 64; m <<= 1) {
            mv = fmaxf(mv, __shfl_xor(mv, m));
            sv += __shfl_xor(sv, m);
        }
        if (l == 0) { mxs[c] = mv; avs[c] = sv * (1.0f / HWSZ); }
    }
    __syncthreads();

    // phase 2: hidden = relu(v @ W1^T); 16 outputs x 16 lanes x 8 channels
    if (tid < 256) {
        int j = tid >> 4, chunk = tid & 15;
        const float* v = (j < 8) ? mxs : avs;
        const float* wrow = se_w1 + (j & 7) * CC + chunk * 8;
        const float* vv = v + chunk * 8;
        float acc = 0.f;
        #pragma unroll
        for (int k = 0; k < 8; ++k) acc += vv[k] * wrow[k];
        #pragma unroll
        for (int m = 1; m < 16; m <<= 1) acc += __shfl_xor(acc, m);
        if (chunk == 0) hid[j] = fmaxf(acc, 0.f);
    }
    __syncthreads();

    // phase 3: ca[c]
    if (tid < CC) {
        float acc = 0.f;
        #pragma unroll
        for (int j = 0; j < 8; ++j) acc += (hid[j] + hid[8 + j]) * se_w2[tid * 8 + j];
        cas[tid] = sigmoidf_(acc);
        ca_out[n * CC + tid] = cas[tid];
    }
    __syncthreads();

    // phase 4: spatial max/sum over channels of out = x*ca (2 half-channel passes)
    if (tid < 2 * HWSZ) {
        int s = tid >> 1, half = tid & 1;
        int c0 = half * 64;
        float mv = -INFINITY, sv = 0.f;
        #pragma unroll 4
        for (int k = 0; k < 64; ++k) {
            float v = x[(c0 + k) * HWSZ + s] * cas[c0 + k];
            mv = fmaxf(mv, v); sv += v;
        }
        smx2[half * HWSZ + s] = mv; sav2[half * HWSZ + s] = sv;
    }
    __syncthreads();

    // phase 5: 49x49 conv (pad 24 = all-pairs) + sigmoid -> sa_out
    if (tid < HWSZ) {
        int y = tid >> 3, xx = tid & 7;
        float acc = sa_b[0];
        for (int iy = 0; iy < HH; ++iy) {
            int wy = iy - y + 24;
            const float* w0 = wbuf + wy * 49;
            const float* w1 = wbuf + 2401 + wy * 49;
            #pragma unroll
            for (int ix = 0; ix < WW; ++ix) {
                int wx = ix - xx + 24;
                int sp = iy * 8 + ix;
                float s0 = fmaxf(smx2[sp], smx2[HWSZ + sp]);
                float s1 = (sav2[sp] + sav2[HWSZ + sp]) * (1.0f / CC);
                acc += s0 * w0[wx] + s1 * w1[wx];
            }
        }
        sa_out[n * HWSZ + tid] = sigmoidf_(acc);
    }
}

// ---------------- Kernel 1b: CBAM apply + transpose, 768 blocks x 256 ----------------
__global__ __launch_bounds__(256) void cbam_apply(
    const float* __restrict__ prob, const float* __restrict__ gal,
    const float* __restrict__ ca_buf, const float* __restrict__ sa_buf,
    __hip_bfloat16* __restrict__ pf_t, __hip_bfloat16* __restrict__ gf_t)
{
    __shared__ unsigned short T[16][136];   // [s_local][c], padded
    __shared__ float sash[16];

    int n = blockIdx.x / 12;
    int s0 = (blockIdx.x % 12) * 16;
    const float* x = (n < 32) ? prob + (size_t)n * CC * HWSZ : gal + (size_t)(n - 32) * CC * HWSZ;
    __hip_bfloat16* dst = (n < 32) ? pf_t + (size_t)n * HWSZ * CC : gf_t + (size_t)(n - 32) * HWSZ * CC;

    int tid = threadIdx.x;
    if (tid < 16) sash[tid] = sa_buf[n * HWSZ + s0 + tid];
    __syncthreads();

    int c = tid >> 1, half = tid & 1;           // c: 0..127, half: 0..1
    float ca = ca_buf[n * CC + c];
    const float* xp = x + c * HWSZ + s0 + half * 8;
    float4 va = *(const float4*)xp;
    float4 vb = *(const float4*)(xp + 4);
    int r0 = half * 8;
    T[r0 + 0][c] = f2bf(va.x * (1.f + ca * sash[r0 + 0]));
    T[r0 + 1][c] = f2bf(va.y * (1.f + ca * sash[r0 + 1]));
    T[r0 + 2][c] = f2bf(va.z * (1.f + ca * sash[r0 + 2]));
    T[r0 + 3][c] = f2bf(va.w * (1.f + ca * sash[r0 + 3]));
    T[r0 + 4][c] = f2bf(vb.x * (1.f + ca * sash[r0 + 4]));
    T[r0 + 5][c] = f2bf(vb.y * (1.f + ca * sash[r0 + 5]));
    T[r0 + 6][c] = f2bf(vb.z * (1.f + ca * sash[r0 + 6]));
    T[r0 + 7][c] = f2bf(vb.w * (1.f + ca * sash[r0 + 7]));
    __syncthreads();

    int s_l = tid >> 4, c8 = (tid & 15) * 8;
    const unsigned int* src = (const unsigned int*)&T[s_l][c8];
    unsigned int* d32 = (unsigned int*)(dst + (s0 + s_l) * CC + c8);
    d32[0] = src[0]; d32[1] = src[1]; d32[2] = src[2]; d32[3] = src[3];
}

// ---------------- Kernel 2: 32x32 dual-MFMA, no staging, no in-loop barriers ----------------
__global__ __launch_bounds__(384, 4) void score_kernel(
    const __hip_bfloat16* __restrict__ pf_t, const __hip_bfloat16* __restrict__ gf_t,
    const float* __restrict__ bn_g, const float* __restrict__ bn_b,
    const float* __restrict__ bn_m, const float* __restrict__ bn_v,
    const float* __restrict__ fc_w, const float* __restrict__ fc_b,
    const float* __restrict__ lbn_g, const float* __restrict__ lbn_b,
    const float* __restrict__ lbn_m, const float* __restrict__ lbn_v,
    float* __restrict__ out)
{
    __shared__ unsigned short M1b[24 * M1LD];   // [hr][s]  max over wr, bf16
    __shared__ unsigned short M2b[HWSZ * M2LD]; // [r][hs]  max over ws, bf16
    __shared__ float red[6], wred[6];

    int bi = blockIdx.x;
    int p = bi >> 5, g = bi & 31;
    int tid = threadIdx.x, l = tid & 63, w = tid >> 6;   // w in 0..5, wave owns rows w*32..w*32+31

    const __hip_bfloat16* A = gf_t + (size_t)g * HWSZ * CC; // [r][c]
    const __hip_bfloat16* B = pf_t + (size_t)p * HWSZ * CC; // [s][c]

    int r32 = l & 31;           // row-in-tile (A) / col s-in-tile (B)
    int koff = (l >> 5) * 8;    // k-offset within 16-wide K step

    // A fragments: wave's 32 rows, all K=128 (8 ks-steps of 16), 32 VGPR
    bf16x8 afr[8];
    {
        const __hip_bfloat16* ap = A + (w * 32 + r32) * CC + koff;
        #pragma unroll
        for (int ks = 0; ks < 8; ++ks) afr[ks] = *(const bf16x8*)(ap + ks * 16);
    }

    const __hip_bfloat16* bp0 = B + r32 * CC + koff;

    for (int st = 0; st < 6; ++st) {
        const __hip_bfloat16* bp = bp0 + st * 32 * CC;
        f32x16 acc1 = {};   // D1[r][s]
        f32x16 acc2 = {};   // D2[s][r] via operand swap
        #pragma unroll
        for (int ks = 0; ks < 8; ++ks) {
            bf16x8 bfr = *(const bf16x8*)(bp + ks * 16);
            acc1 = __builtin_amdgcn_mfma_f32_32x32x16_bf16(afr[ks], bfr, acc1, 0, 0, 0);
            acc2 = __builtin_amdgcn_mfma_f32_32x32x16_bf16(bfr, afr[ks], acc2, 0, 0, 0);
        }

        // 32x32 D layout (m74/m101): col = l&31, row = (reg&3) + 8*(reg>>2) + 4*(l>>5)
        // M1[hr][s]: max over 8 r-rows per hr group q: in-lane (reg&3) + shfl_xor(32)
        #pragma unroll
        for (int q = 0; q < 4; ++q) {
            float m = fmaxf(fmaxf(acc1[4 * q + 0], acc1[4 * q + 1]),
                            fmaxf(acc1[4 * q + 2], acc1[4 * q + 3]));
            m = fmaxf(m, __shfl_xor(m, 32));
            if (l < 32)
                M1b[(w * 4 + q) * M1LD + st * 32 + l] = f2bf(m);
        }

        // M2[r][hs]: same reduction on the swapped tile; 4 hs values pack to one b64 write
        unsigned short pk0, pk1, pk2, pk3;
        {
            float m0 = fmaxf(fmaxf(acc2[0], acc2[1]), fmaxf(acc2[2], acc2[3]));
            float m1 = fmaxf(fmaxf(acc2[4], acc2[5]), fmaxf(acc2[6], acc2[7]));
            float m2 = fmaxf(fmaxf(acc2[8], acc2[9]), fmaxf(acc2[10], acc2[11]));
            float m3 = fmaxf(fmaxf(acc2[12], acc2[13]), fmaxf(acc2[14], acc2[15]));
            m0 = fmaxf(m0, __shfl_xor(m0, 32));
            m1 = fmaxf(m1, __shfl_xor(m1, 32));
            m2 = fmaxf(m2, __shfl_xor(m2, 32));
            m3 = fmaxf(m3, __shfl_xor(m3, 32));
            pk0 = f2bf(m0); pk1 = f2bf(m1); pk2 = f2bf(m2); pk3 = f2bf(m3);
        }
        if (l < 32) {
            ushort4 v; v.x = pk0; v.y = pk1; v.z = pk2; v.w = pk3;
            *(ushort4*)(&M2b[(w * 32 + l) * M2LD + st * 4]) = v;   // 8B-aligned: 56r+8st
        }
    }
    __syncthreads();

    // windowed max (6 consecutive h rows, start clip(h-3,0,18)) + fc_w-weighted sum
    float part = 0.f, wpart = 0.f;
    if (tid < HWSZ) {
        int h = tid >> 3;
        int st0 = h - 3; if (st0 < 0) st0 = 0; if (st0 > 18) st0 = 18;
        float v1 = -INFINITY, v2 = -INFINITY;
        #pragma unroll
        for (int i = 0; i < 6; ++i) {
            v1 = fmaxf(v1, bf2f(M1b[(st0 + i) * M1LD + tid]));
            v2 = fmaxf(v2, bf2f(M2b[tid * M2LD + st0 + i]));
        }
        float fw = fc_w[tid];
        part = fw * (v1 + v2);
        wpart = fw;
    }
    #pragma unroll
    for (int m = 1; m < 64; m <<= 1) {
        part  += __shfl_xor(part, m);
        wpart += __shfl_xor(wpart, m);
    }
    if (l == 0) { red[w] = part; wred[w] = wpart; }
    __syncthreads();

    if (tid == 0) {
        float total = red[0] + red[1] + red[2] + red[3] + red[4] + red[5];
        float Wsum  = wred[0] + wred[1] + wred[2] + wred[3] + wred[4] + wred[5];
        float k1 = bn_g[0] * rsqrtf(bn_v[0] + EPSV);
        float Y = k1 * total + 2.f * ((bn_b[0] - k1 * bn_m[0]) * Wsum + fc_b[0]);
        float kl = lbn_g[0] * rsqrtf(lbn_v[0] + EPSV);
        float Z = (Y - lbn_m[0]) * kl + lbn_b[0];
        out[bi] = 1.f / (1.f + expf(-Z));
    }
}

extern "C" void kernel_launch(void* const* d_in, const int* in_sizes, int n_in,
                              void* d_out, int out_size, void* d_ws, size_t ws_size,
                              hipStream_t stream)
{
    const float* prob  = (const float*)d_in[0];
    const float* gal   = (const float*)d_in[1];
    const float* se_w1 = (const float*)d_in[2];
    const float* se_w2 = (const float*)d_in[3];
    const float* sa_w  = (const float*)d_in[4];
    const float* sa_b  = (const float*)d_in[5];
    const float* bn_g  = (const float*)d_in[6];
    const float* bn_b  = (const float*)d_in[7];
    const float* bn_m  = (const float*)d_in[8];
    const float* bn_v  = (const float*)d_in[9];
    const float* fc_w  = (const float*)d_in[10];
    const float* fc_b  = (const float*)d_in[11];
    const float* lbn_g = (const float*)d_in[12];
    const float* lbn_b = (const float*)d_in[13];
    const float* lbn_m = (const float*)d_in[14];
    const float* lbn_v = (const float*)d_in[15];

    __hip_bfloat16* pf_t = (__hip_bfloat16*)d_ws;             // [32][192][128] bf16
    __hip_bfloat16* gf_t = pf_t + (size_t)32 * HWSZ * CC;     // [32][192][128] bf16
    float* ca_buf = (float*)(gf_t + (size_t)32 * HWSZ * CC);  // [64][128] f32
    float* sa_buf = ca_buf + 64 * CC;                         // [64][192] f32
    float* out = (float*)d_out;

    cbam_stats<<<64, 512, 0, stream>>>(prob, gal, se_w1, se_w2, sa_w, sa_b, ca_buf, sa_buf);
    cbam_apply<<<768, 256, 0, stream>>>(prob, gal, ca_buf, sa_buf, pf_t, gf_t);
    score_kernel<<<1024, 384, 0, stream>>>(pf_t, gf_t, bn_g, bn_b, bn_m, bn_v,
                                           fc_w, fc_b, lbn_g, lbn_b, lbn_m, lbn_v, out);
}

// Round 12
// 137.871 us; speedup vs baseline: 1.1262x; 1.1262x over previous
//
#include <hip/hip_runtime.h>
#include <hip/hip_bf16.h>

#define HH 24
#define WW 8
#define HWSZ 192
#define CC 128
#define EPSV 1e-5f

#define M1LD 200   // M1 [24][M1LD] bf16
#define M2LD 28    // M2 [192][M2LD] bf16

typedef __attribute__((ext_vector_type(8))) short bf16x8;
typedef __attribute__((ext_vector_type(4))) float f32x4;

__device__ __forceinline__ float sigmoidf_(float x) { return 1.0f / (1.0f + expf(-x)); }

__device__ __forceinline__ unsigned short f2bf(float f) {
    unsigned int u = __float_as_uint(f);
    unsigned int r = (u + 0x7fffu + ((u >> 16) & 1u)) >> 16;
    return (unsigned short)r;
}
__device__ __forceinline__ float bf2f(unsigned short s) {
    return __uint_as_float((unsigned int)s << 16);
}

// ---------------- Kernel 1a: CBAM stats (phases 1-5), 64 blocks x 512 ----------------
__global__ __launch_bounds__(512) void cbam_stats(
    const float* __restrict__ prob, const float* __restrict__ gal,
    const float* __restrict__ se_w1, const float* __restrict__ se_w2,
    const float* __restrict__ sa_w, const float* __restrict__ sa_b,
    float* __restrict__ ca_out, float* __restrict__ sa_out)
{
    __shared__ float mxs[CC], avs[CC], hid[16], cas[CC];
    __shared__ float smx2[2 * HWSZ], sav2[2 * HWSZ];
    __shared__ float wbuf[2 * 49 * 49];

    int n = blockIdx.x;
    const float* x = (n < 32) ? prob + (size_t)n * CC * HWSZ : gal + (size_t)(n - 32) * CC * HWSZ;

    int tid = threadIdx.x, l = tid & 63, w = tid >> 6;

    for (int i = tid; i < 2 * 49 * 49; i += 512) wbuf[i] = sa_w[i];

    // phase 1: per-channel max/mean over 192 spatial (8 waves x 16 channels)
    for (int i = 0; i < 16; ++i) {
        int c = w * 16 + i;
        const float* row = x + c * HWSZ;
        float a = row[l], b = row[l + 64], d = row[l + 128];
        float mv = fmaxf(a, fmaxf(b, d));
        float sv = a + b + d;
        #pragma unroll
        for (int m = 1; m < 64; m <<= 1) {
            mv = fmaxf(mv, __shfl_xor(mv, m));
            sv += __shfl_xor(sv, m);
        }
        if (l == 0) { mxs[c] = mv; avs[c] = sv * (1.0f / HWSZ); }
    }
    __syncthreads();

    // phase 2: hidden = relu(v @ W1^T); 16 outputs x 16 lanes x 8 channels
    if (tid < 256) {
        int j = tid >> 4, chunk = tid & 15;
        const float* v = (j < 8) ? mxs : avs;
        const float* wrow = se_w1 + (j & 7) * CC + chunk * 8;
        const float* vv = v + chunk * 8;
        float acc = 0.f;
        #pragma unroll
        for (int k = 0; k < 8; ++k) acc += vv[k] * wrow[k];
        #pragma unroll
        for (int m = 1; m < 16; m <<= 1) acc += __shfl_xor(acc, m);
        if (chunk == 0) hid[j] = fmaxf(acc, 0.f);
    }
    __syncthreads();

    // phase 3: ca[c]
    if (tid < CC) {
        float acc = 0.f;
        #pragma unroll
        for (int j = 0; j < 8; ++j) acc += (hid[j] + hid[8 + j]) * se_w2[tid * 8 + j];
        cas[tid] = sigmoidf_(acc);
        ca_out[n * CC + tid] = cas[tid];
    }
    __syncthreads();

    // phase 4: spatial max/sum over channels of out = x*ca (2 half-channel passes)
    if (tid < 2 * HWSZ) {
        int s = tid >> 1, half = tid & 1;
        int c0 = half * 64;
        float mv = -INFINITY, sv = 0.f;
        #pragma unroll 4
        for (int k = 0; k < 64; ++k) {
            float v = x[(c0 + k) * HWSZ + s] * cas[c0 + k];
            mv = fmaxf(mv, v); sv += v;
        }
        smx2[half * HWSZ + s] = mv; sav2[half * HWSZ + s] = sv;
    }
    __syncthreads();

    // phase 5: 49x49 conv (pad 24 = all-pairs) + sigmoid -> sa_out
    if (tid < HWSZ) {
        int y = tid >> 3, xx = tid & 7;
        float acc = sa_b[0];
        for (int iy = 0; iy < HH; ++iy) {
            int wy = iy - y + 24;
            const float* w0 = wbuf + wy * 49;
            const float* w1 = wbuf + 2401 + wy * 49;
            #pragma unroll
            for (int ix = 0; ix < WW; ++ix) {
                int wx = ix - xx + 24;
                int sp = iy * 8 + ix;
                float s0 = fmaxf(smx2[sp], smx2[HWSZ + sp]);
                float s1 = (sav2[sp] + sav2[HWSZ + sp]) * (1.0f / CC);
                acc += s0 * w0[wx] + s1 * w1[wx];
            }
        }
        sa_out[n * HWSZ + tid] = sigmoidf_(acc);
    }
}

// ---------------- Kernel 1b: CBAM apply + transpose, 768 blocks x 256 ----------------
__global__ __launch_bounds__(256) void cbam_apply(
    const float* __restrict__ prob, const float* __restrict__ gal,
    const float* __restrict__ ca_buf, const float* __restrict__ sa_buf,
    __hip_bfloat16* __restrict__ pf_t, __hip_bfloat16* __restrict__ gf_t)
{
    __shared__ unsigned short T[16][136];   // [s_local][c], padded
    __shared__ float sash[16];

    int n = blockIdx.x / 12;
    int s0 = (blockIdx.x % 12) * 16;
    const float* x = (n < 32) ? prob + (size_t)n * CC * HWSZ : gal + (size_t)(n - 32) * CC * HWSZ;
    __hip_bfloat16* dst = (n < 32) ? pf_t + (size_t)n * HWSZ * CC : gf_t + (size_t)(n - 32) * HWSZ * CC;

    int tid = threadIdx.x;
    if (tid < 16) sash[tid] = sa_buf[n * HWSZ + s0 + tid];
    __syncthreads();

    int c = tid >> 1, half = tid & 1;           // c: 0..127, half: 0..1
    float ca = ca_buf[n * CC + c];
    const float* xp = x + c * HWSZ + s0 + half * 8;
    float4 va = *(const float4*)xp;
    float4 vb = *(const float4*)(xp + 4);
    int r0 = half * 8;
    T[r0 + 0][c] = f2bf(va.x * (1.f + ca * sash[r0 + 0]));
    T[r0 + 1][c] = f2bf(va.y * (1.f + ca * sash[r0 + 1]));
    T[r0 + 2][c] = f2bf(va.z * (1.f + ca * sash[r0 + 2]));
    T[r0 + 3][c] = f2bf(va.w * (1.f + ca * sash[r0 + 3]));
    T[r0 + 4][c] = f2bf(vb.x * (1.f + ca * sash[r0 + 4]));
    T[r0 + 5][c] = f2bf(vb.y * (1.f + ca * sash[r0 + 5]));
    T[r0 + 6][c] = f2bf(vb.z * (1.f + ca * sash[r0 + 6]));
    T[r0 + 7][c] = f2bf(vb.w * (1.f + ca * sash[r0 + 7]));
    __syncthreads();

    int s_l = tid >> 4, c8 = (tid & 15) * 8;
    const unsigned int* src = (const unsigned int*)&T[s_l][c8];
    unsigned int* d32 = (unsigned int*)(dst + (s0 + s_l) * CC + c8);
    d32[0] = src[0]; d32[1] = src[1]; d32[2] = src[2]; d32[3] = src[3];
}

// ---- Kernel 2: 16x16 dual-MFMA, 3-tile double-buffered B staging (44.8KB LDS) ----
__global__ __launch_bounds__(384, 4) void score_kernel(
    const __hip_bfloat16* __restrict__ pf_t, const __hip_bfloat16* __restrict__ gf_t,
    const float* __restrict__ bn_g, const float* __restrict__ bn_b,
    const float* __restrict__ bn_m, const float* __restrict__ bn_v,
    const float* __restrict__ fc_w, const float* __restrict__ fc_b,
    const float* __restrict__ lbn_g, const float* __restrict__ lbn_b,
    const float* __restrict__ lbn_m, const float* __restrict__ lbn_v,
    float* __restrict__ out)
{
    // 2 buffers x 3 s-tiles x 4KB (chunk-major: frag ks at byte t*4096 + ks*1024 + l*16)
    __shared__ __align__(16) char bstage[2][3 * 4096];
    __shared__ unsigned short M1b[24 * M1LD];   // [hr][s]  max over wr, bf16
    __shared__ unsigned short M2b[HWSZ * M2LD]; // [r][hs]  max over ws, bf16
    __shared__ float red[6], wred[6];

    int bi = blockIdx.x;
    int p = bi >> 5, g = bi & 31;
    int tid = threadIdx.x, l = tid & 63, w = tid >> 6;   // w in 0..5

    const __hip_bfloat16* A = gf_t + (size_t)g * HWSZ * CC; // [r][c]
    const __hip_bfloat16* B = pf_t + (size_t)p * HWSZ * CC; // [s][c]

    // stage group grp_ (3 tiles, 12 x 1KB chunks; 2 chunks per wave) into buf_
    // LDS byte (t*4096 + q*1024 + i*16) <=> global elem ((3*grp+t)*16 + (i&15))*CC + (q*4+(i>>4))*8
    #define STAGE_G(buf_, grp_)                                                          \
        {                                                                                \
            _Pragma("unroll")                                                            \
            for (int i_ = 0; i_ < 2; ++i_) {                                             \
                int idx_ = w * 2 + i_;              /* 0..11: t = idx>>2, q = idx&3 */   \
                const __hip_bfloat16* src_ = B + (((grp_) * 3 + (idx_ >> 2)) * 16        \
                                                  + (l & 15)) * CC                       \
                                               + ((idx_ & 3) * 4 + (l >> 4)) * 8;        \
                __builtin_amdgcn_global_load_lds(                                        \
                    (const __attribute__((address_space(1))) void*)src_,                 \
                    (__attribute__((address_space(3))) void*)(&bstage[buf_][idx_ * 1024]),\
                    16, 0, 0);                                                           \
            }                                                                            \
        }

    // prologue: stage group 0; A-frag register loads overlap the staging latency
    STAGE_G(0, 0)

    int row_a = l & 15;
    int koff = (l >> 4) * 8;
    bf16x8 afr[2][4];
    #pragma unroll
    for (int rt = 0; rt < 2; ++rt) {
        const __hip_bfloat16* ap = A + (w * 32 + rt * 16 + row_a) * CC + koff;
        #pragma unroll
        for (int ks = 0; ks < 4; ++ks)
            afr[rt][ks] = *(const bf16x8*)(ap + ks * 32);
    }
    __syncthreads();   // group 0 staged

    for (int grp = 0; grp < 4; ++grp) {
        int cur = grp & 1;
        if (grp < 3) STAGE_G(cur ^ 1, grp + 1)   // DMA next group into other buffer

        #pragma unroll
        for (int t = 0; t < 3; ++t) {
            int st = grp * 3 + t;
            const char* bb = bstage[cur] + t * 4096;
            bf16x8 b0 = *(const bf16x8*)(bb + 0 * 1024 + l * 16);
            bf16x8 b1 = *(const bf16x8*)(bb + 1 * 1024 + l * 16);
            bf16x8 b2 = *(const bf16x8*)(bb + 2 * 1024 + l * 16);
            bf16x8 b3 = *(const bf16x8*)(bb + 3 * 1024 + l * 16);

            #pragma unroll
            for (int rt = 0; rt < 2; ++rt) {
                // D1[r][s] for M1, D2[s][r] (operand swap) for M2 — each reduction is
                // in-lane max over 4 regs + ONE shfl_xor(16).
                f32x4 acc1 = {0.f, 0.f, 0.f, 0.f};
                f32x4 acc2 = {0.f, 0.f, 0.f, 0.f};
                acc1 = __builtin_amdgcn_mfma_f32_16x16x32_bf16(afr[rt][0], b0, acc1, 0, 0, 0);
                acc2 = __builtin_amdgcn_mfma_f32_16x16x32_bf16(b0, afr[rt][0], acc2, 0, 0, 0);
                acc1 = __builtin_amdgcn_mfma_f32_16x16x32_bf16(afr[rt][1], b1, acc1, 0, 0, 0);
                acc2 = __builtin_amdgcn_mfma_f32_16x16x32_bf16(b1, afr[rt][1], acc2, 0, 0, 0);
                acc1 = __builtin_amdgcn_mfma_f32_16x16x32_bf16(afr[rt][2], b2, acc1, 0, 0, 0);
                acc2 = __builtin_amdgcn_mfma_f32_16x16x32_bf16(b2, afr[rt][2], acc2, 0, 0, 0);
                acc1 = __builtin_amdgcn_mfma_f32_16x16x32_bf16(afr[rt][3], b3, acc1, 0, 0, 0);
                acc2 = __builtin_amdgcn_mfma_f32_16x16x32_bf16(b3, afr[rt][3], acc2, 0, 0, 0);

                int RT = w * 2 + rt;

                // M1[hr][s]: D1 row=(l>>4)*4+reg (=r_sub), col=l&15 (=s_sub)
                float mrow = fmaxf(fmaxf(acc1[0], acc1[1]), fmaxf(acc1[2], acc1[3]));
                mrow = fmaxf(mrow, __shfl_xor(mrow, 16));
                if (((l >> 4) & 1) == 0)
                    M1b[(2 * RT + (l >> 5)) * M1LD + st * 16 + (l & 15)] = f2bf(mrow);

                // M2[r][hs]: D2 row=(l>>4)*4+reg (=s_sub), col=l&15 (=r_sub)
                float mcol = fmaxf(fmaxf(acc2[0], acc2[1]), fmaxf(acc2[2], acc2[3]));
                mcol = fmaxf(mcol, __shfl_xor(mcol, 16));
                if (((l >> 4) & 1) == 0)
                    M2b[(RT * 16 + (l & 15)) * M2LD + st * 2 + (l >> 5)] = f2bf(mcol);
            }
        }
        // group boundary: own DMA drained (vmcnt) + all waves done reading bstage[cur]
        __syncthreads();
    }

    // windowed max (6 consecutive h rows, start clip(h-3,0,18)) + fc_w-weighted sum
    float part = 0.f, wpart = 0.f;
    if (tid < HWSZ) {
        int h = tid >> 3;
        int st0 = h - 3; if (st0 < 0) st0 = 0; if (st0 > 18) st0 = 18;
        float v1 = -INFINITY, v2 = -INFINITY;
        #pragma unroll
        for (int i = 0; i < 6; ++i) {
            v1 = fmaxf(v1, bf2f(M1b[(st0 + i) * M1LD + tid]));
            v2 = fmaxf(v2, bf2f(M2b[tid * M2LD + st0 + i]));
        }
        float fw = fc_w[tid];
        part = fw * (v1 + v2);
        wpart = fw;
    }
    #pragma unroll
    for (int m = 1; m < 64; m <<= 1) {
        part  += __shfl_xor(part, m);
        wpart += __shfl_xor(wpart, m);
    }
    if (l == 0) { red[w] = part; wred[w] = wpart; }
    __syncthreads();

    if (tid == 0) {
        float total = red[0] + red[1] + red[2] + red[3] + red[4] + red[5];
        float Wsum  = wred[0] + wred[1] + wred[2] + wred[3] + wred[4] + wred[5];
        float k1 = bn_g[0] * rsqrtf(bn_v[0] + EPSV);
        float Y = k1 * total + 2.f * ((bn_b[0] - k1 * bn_m[0]) * Wsum + fc_b[0]);
        float kl = lbn_g[0] * rsqrtf(lbn_v[0] + EPSV);
        float Z = (Y - lbn_m[0]) * kl + lbn_b[0];
        out[bi] = 1.f / (1.f + expf(-Z));
    }
}

extern "C" void kernel_launch(void* const* d_in, const int* in_sizes, int n_in,
                              void* d_out, int out_size, void* d_ws, size_t ws_size,
                              hipStream_t stream)
{
    const float* prob  = (const float*)d_in[0];
    const float* gal   = (const float*)d_in[1];
    const float* se_w1 = (const float*)d_in[2];
    const float* se_w2 = (const float*)d_in[3];
    const float* sa_w  = (const float*)d_in[4];
    const float* sa_b  = (const float*)d_in[5];
    const float* bn_g  = (const float*)d_in[6];
    const float* bn_b  = (const float*)d_in[7];
    const float* bn_m  = (const float*)d_in[8];
    const float* bn_v  = (const float*)d_in[9];
    const float* fc_w  = (const float*)d_in[10];
    const float* fc_b  = (const float*)d_in[11];
    const float* lbn_g = (const float*)d_in[12];
    const float* lbn_b = (const float*)d_in[13];
    const float* lbn_m = (const float*)d_in[14];
    const float* lbn_v = (const float*)d_in[15];

    __hip_bfloat16* pf_t = (__hip_bfloat16*)d_ws;             // [32][192][128] bf16
    __hip_bfloat16* gf_t = pf_t + (size_t)32 * HWSZ * CC;     // [32][192][128] bf16
    float* ca_buf = (float*)(gf_t + (size_t)32 * HWSZ * CC);  // [64][128] f32
    float* sa_buf = ca_buf + 64 * CC;                         // [64][192] f32
    float* out = (float*)d_out;

    cbam_stats<<<64, 512, 0, stream>>>(prob, gal, se_w1, se_w2, sa_w, sa_b, ca_buf, sa_buf);
    cbam_apply<<<768, 256, 0, stream>>>(prob, gal, ca_buf, sa_buf, pf_t, gf_t);
    score_kernel<<<1024, 384, 0, stream>>>(pf_t, gf_t, bn_g, bn_b, bn_m, bn_v,
                                           fc_w, fc_b, lbn_g, lbn_b, lbn_m, lbn_v, out);
}

// Round 13
// 135.198 us; speedup vs baseline: 1.1484x; 1.0198x over previous
//
#include <hip/hip_runtime.h>
#include <hip/hip_bf16.h>

#define HH 24
#define WW 8
#define HWSZ 192
#define CC 128
#define EPSV 1e-5f

#define M1LD 200   // M1 [24][M1LD] bf16
#define M2LD 28    // M2 [192][M2LD] bf16

typedef __attribute__((ext_vector_type(8))) short bf16x8;
typedef __attribute__((ext_vector_type(4))) float f32x4;

__device__ __forceinline__ float sigmoidf_(float x) { return 1.0f / (1.0f + expf(-x)); }

__device__ __forceinline__ unsigned short f2bf(float f) {
    unsigned int u = __float_as_uint(f);
    unsigned int r = (u + 0x7fffu + ((u >> 16) & 1u)) >> 16;
    return (unsigned short)r;
}
__device__ __forceinline__ float bf2f(unsigned short s) {
    return __uint_as_float((unsigned int)s << 16);
}

// ---------------- Kernel 1a: CBAM stats (phases 1-5), 64 blocks x 512 ----------------
__global__ __launch_bounds__(512) void cbam_stats(
    const float* __restrict__ prob, const float* __restrict__ gal,
    const float* __restrict__ se_w1, const float* __restrict__ se_w2,
    const float* __restrict__ sa_w, const float* __restrict__ sa_b,
    float* __restrict__ ca_out, float* __restrict__ sa_out)
{
    __shared__ float mxs[CC], avs[CC], hid[16], cas[CC];
    __shared__ float smx2[2 * HWSZ], sav2[2 * HWSZ];
    __shared__ float wbuf[2 * 49 * 49];

    int n = blockIdx.x;
    const float* x = (n < 32) ? prob + (size_t)n * CC * HWSZ : gal + (size_t)(n - 32) * CC * HWSZ;

    int tid = threadIdx.x, l = tid & 63, w = tid >> 6;

    for (int i = tid; i < 2 * 49 * 49; i += 512) wbuf[i] = sa_w[i];

    // phase 1: per-channel max/mean over 192 spatial (8 waves x 16 channels)
    for (int i = 0; i < 16; ++i) {
        int c = w * 16 + i;
        const float* row = x + c * HWSZ;
        float a = row[l], b = row[l + 64], d = row[l + 128];
        float mv = fmaxf(a, fmaxf(b, d));
        float sv = a + b + d;
        #pragma unroll
        for (int m = 1; m < 64; m <<= 1) {
            mv = fmaxf(mv, __shfl_xor(mv, m));
            sv += __shfl_xor(sv, m);
        }
        if (l == 0) { mxs[c] = mv; avs[c] = sv * (1.0f / HWSZ); }
    }
    __syncthreads();

    // phase 2: hidden = relu(v @ W1^T); 16 outputs x 16 lanes x 8 channels
    if (tid < 256) {
        int j = tid >> 4, chunk = tid & 15;
        const float* v = (j < 8) ? mxs : avs;
        const float* wrow = se_w1 + (j & 7) * CC + chunk * 8;
        const float* vv = v + chunk * 8;
        float acc = 0.f;
        #pragma unroll
        for (int k = 0; k < 8; ++k) acc += vv[k] * wrow[k];
        #pragma unroll
        for (int m = 1; m < 16; m <<= 1) acc += __shfl_xor(acc, m);
        if (chunk == 0) hid[j] = fmaxf(acc, 0.f);
    }
    __syncthreads();

    // phase 3: ca[c]
    if (tid < CC) {
        float acc = 0.f;
        #pragma unroll
        for (int j = 0; j < 8; ++j) acc += (hid[j] + hid[8 + j]) * se_w2[tid * 8 + j];
        cas[tid] = sigmoidf_(acc);
        ca_out[n * CC + tid] = cas[tid];
    }
    __syncthreads();

    // phase 4: spatial max/sum over channels of out = x*ca (2 half-channel passes)
    if (tid < 2 * HWSZ) {
        int s = tid >> 1, half = tid & 1;
        int c0 = half * 64;
        float mv = -INFINITY, sv = 0.f;
        #pragma unroll 4
        for (int k = 0; k < 64; ++k) {
            float v = x[(c0 + k) * HWSZ + s] * cas[c0 + k];
            mv = fmaxf(mv, v); sv += v;
        }
        smx2[half * HWSZ + s] = mv; sav2[half * HWSZ + s] = sv;
    }
    __syncthreads();

    // phase 5: 49x49 conv (pad 24 = all-pairs) + sigmoid -> sa_out
    if (tid < HWSZ) {
        int y = tid >> 3, xx = tid & 7;
        float acc = sa_b[0];
        for (int iy = 0; iy < HH; ++iy) {
            int wy = iy - y + 24;
            const float* w0 = wbuf + wy * 49;
            const float* w1 = wbuf + 2401 + wy * 49;
            #pragma unroll
            for (int ix = 0; ix < WW; ++ix) {
                int wx = ix - xx + 24;
                int sp = iy * 8 + ix;
                float s0 = fmaxf(smx2[sp], smx2[HWSZ + sp]);
                float s1 = (sav2[sp] + sav2[HWSZ + sp]) * (1.0f / CC);
                acc += s0 * w0[wx] + s1 * w1[wx];
            }
        }
        sa_out[n * HWSZ + tid] = sigmoidf_(acc);
    }
}

// ---------------- Kernel 1b: CBAM apply + transpose, 768 blocks x 256 ----------------
__global__ __launch_bounds__(256) void cbam_apply(
    const float* __restrict__ prob, const float* __restrict__ gal,
    const float* __restrict__ ca_buf, const float* __restrict__ sa_buf,
    __hip_bfloat16* __restrict__ pf_t, __hip_bfloat16* __restrict__ gf_t)
{
    __shared__ unsigned short T[16][136];   // [s_local][c], padded
    __shared__ float sash[16];

    int n = blockIdx.x / 12;
    int s0 = (blockIdx.x % 12) * 16;
    const float* x = (n < 32) ? prob + (size_t)n * CC * HWSZ : gal + (size_t)(n - 32) * CC * HWSZ;
    __hip_bfloat16* dst = (n < 32) ? pf_t + (size_t)n * HWSZ * CC : gf_t + (size_t)(n - 32) * HWSZ * CC;

    int tid = threadIdx.x;
    if (tid < 16) sash[tid] = sa_buf[n * HWSZ + s0 + tid];
    __syncthreads();

    int c = tid >> 1, half = tid & 1;           // c: 0..127, half: 0..1
    float ca = ca_buf[n * CC + c];
    const float* xp = x + c * HWSZ + s0 + half * 8;
    float4 va = *(const float4*)xp;
    float4 vb = *(const float4*)(xp + 4);
    int r0 = half * 8;
    T[r0 + 0][c] = f2bf(va.x * (1.f + ca * sash[r0 + 0]));
    T[r0 + 1][c] = f2bf(va.y * (1.f + ca * sash[r0 + 1]));
    T[r0 + 2][c] = f2bf(va.z * (1.f + ca * sash[r0 + 2]));
    T[r0 + 3][c] = f2bf(va.w * (1.f + ca * sash[r0 + 3]));
    T[r0 + 4][c] = f2bf(vb.x * (1.f + ca * sash[r0 + 4]));
    T[r0 + 5][c] = f2bf(vb.y * (1.f + ca * sash[r0 + 5]));
    T[r0 + 6][c] = f2bf(vb.z * (1.f + ca * sash[r0 + 6]));
    T[r0 + 7][c] = f2bf(vb.w * (1.f + ca * sash[r0 + 7]));
    __syncthreads();

    int s_l = tid >> 4, c8 = (tid & 15) * 8;
    const unsigned int* src = (const unsigned int*)&T[s_l][c8];
    unsigned int* d32 = (unsigned int*)(dst + (s0 + s_l) * CC + c8);
    d32[0] = src[0]; d32[1] = src[1]; d32[2] = src[2]; d32[3] = src[3];
}

// ---- Kernel 2: 16x16 dual-MFMA, 2-tile double-buffered B staging (36.8KB LDS,
// 4 blocks/CU => entire 1024-block grid resident, no tail round) ----
__global__ __launch_bounds__(384, 6) void score_kernel(
    const __hip_bfloat16* __restrict__ pf_t, const __hip_bfloat16* __restrict__ gf_t,
    const float* __restrict__ bn_g, const float* __restrict__ bn_b,
    const float* __restrict__ bn_m, const float* __restrict__ bn_v,
    const float* __restrict__ fc_w, const float* __restrict__ fc_b,
    const float* __restrict__ lbn_g, const float* __restrict__ lbn_b,
    const float* __restrict__ lbn_m, const float* __restrict__ lbn_v,
    float* __restrict__ out)
{
    // 2 buffers x 2 s-tiles x 4KB (chunk-major: frag ks at byte t*4096 + ks*1024 + l*16)
    __shared__ __align__(16) char bstage[2][2 * 4096];
    __shared__ unsigned short M1b[24 * M1LD];   // [hr][s]  max over wr, bf16
    __shared__ unsigned short M2b[HWSZ * M2LD]; // [r][hs]  max over ws, bf16
    __shared__ float red[6], wred[6];

    int bi = blockIdx.x;
    int p = bi >> 5, g = bi & 31;
    int tid = threadIdx.x, l = tid & 63, w = tid >> 6;   // w in 0..5

    const __hip_bfloat16* A = gf_t + (size_t)g * HWSZ * CC; // [r][c]
    const __hip_bfloat16* B = pf_t + (size_t)p * HWSZ * CC; // [s][c]

    // stage group grp_ (2 tiles, 8 x 1KB chunks; waves 0-3 stage 2 each) into buf_
    // LDS byte (t*4096 + q*1024 + i*16) <=> global elem ((2*grp+t)*16 + (i&15))*CC + (q*4+(i>>4))*8
    #define STAGE_G(buf_, grp_)                                                          \
        if (w < 4) {                                                                     \
            _Pragma("unroll")                                                            \
            for (int i_ = 0; i_ < 2; ++i_) {                                             \
                int idx_ = w * 2 + i_;              /* 0..7: t = idx>>2, q = idx&3 */    \
                const __hip_bfloat16* src_ = B + (((grp_) * 2 + (idx_ >> 2)) * 16        \
                                                  + (l & 15)) * CC                       \
                                               + ((idx_ & 3) * 4 + (l >> 4)) * 8;        \
                __builtin_amdgcn_global_load_lds(                                        \
                    (const __attribute__((address_space(1))) void*)src_,                 \
                    (__attribute__((address_space(3))) void*)(&bstage[buf_][idx_ * 1024]),\
                    16, 0, 0);                                                           \
            }                                                                            \
        }

    // prologue: stage group 0; A-frag register loads overlap the staging latency
    STAGE_G(0, 0)

    int row_a = l & 15;
    int koff = (l >> 4) * 8;
    bf16x8 afr[2][4];
    #pragma unroll
    for (int rt = 0; rt < 2; ++rt) {
        const __hip_bfloat16* ap = A + (w * 32 + rt * 16 + row_a) * CC + koff;
        #pragma unroll
        for (int ks = 0; ks < 4; ++ks)
            afr[rt][ks] = *(const bf16x8*)(ap + ks * 32);
    }
    __syncthreads();   // group 0 staged

    for (int grp = 0; grp < 6; ++grp) {
        int cur = grp & 1;
        if (grp < 5) STAGE_G(cur ^ 1, grp + 1)   // DMA next group into other buffer

        #pragma unroll
        for (int t = 0; t < 2; ++t) {
            int st = grp * 2 + t;
            const char* bb = bstage[cur] + t * 4096;
            bf16x8 b0 = *(const bf16x8*)(bb + 0 * 1024 + l * 16);
            bf16x8 b1 = *(const bf16x8*)(bb + 1 * 1024 + l * 16);
            bf16x8 b2 = *(const bf16x8*)(bb + 2 * 1024 + l * 16);
            bf16x8 b3 = *(const bf16x8*)(bb + 3 * 1024 + l * 16);

            #pragma unroll
            for (int rt = 0; rt < 2; ++rt) {
                // D1[r][s] for M1, D2[s][r] (operand swap) for M2 — each reduction is
                // in-lane max over 4 regs + ONE shfl_xor(16).
                f32x4 acc1 = {0.f, 0.f, 0.f, 0.f};
                f32x4 acc2 = {0.f, 0.f, 0.f, 0.f};
                acc1 = __builtin_amdgcn_mfma_f32_16x16x32_bf16(afr[rt][0], b0, acc1, 0, 0, 0);
                acc2 = __builtin_amdgcn_mfma_f32_16x16x32_bf16(b0, afr[rt][0], acc2, 0, 0, 0);
                acc1 = __builtin_amdgcn_mfma_f32_16x16x32_bf16(afr[rt][1], b1, acc1, 0, 0, 0);
                acc2 = __builtin_amdgcn_mfma_f32_16x16x32_bf16(b1, afr[rt][1], acc2, 0, 0, 0);
                acc1 = __builtin_amdgcn_mfma_f32_16x16x32_bf16(afr[rt][2], b2, acc1, 0, 0, 0);
                acc2 = __builtin_amdgcn_mfma_f32_16x16x32_bf16(b2, afr[rt][2], acc2, 0, 0, 0);
                acc1 = __builtin_amdgcn_mfma_f32_16x16x32_bf16(afr[rt][3], b3, acc1, 0, 0, 0);
                acc2 = __builtin_amdgcn_mfma_f32_16x16x32_bf16(b3, afr[rt][3], acc2, 0, 0, 0);

                int RT = w * 2 + rt;

                // M1[hr][s]: D1 row=(l>>4)*4+reg (=r_sub), col=l&15 (=s_sub)
                float mrow = fmaxf(fmaxf(acc1[0], acc1[1]), fmaxf(acc1[2], acc1[3]));
                mrow = fmaxf(mrow, __shfl_xor(mrow, 16));
                if (((l >> 4) & 1) == 0)
                    M1b[(2 * RT + (l >> 5)) * M1LD + st * 16 + (l & 15)] = f2bf(mrow);

                // M2[r][hs]: D2 row=(l>>4)*4+reg (=s_sub), col=l&15 (=r_sub)
                float mcol = fmaxf(fmaxf(acc2[0], acc2[1]), fmaxf(acc2[2], acc2[3]));
                mcol = fmaxf(mcol, __shfl_xor(mcol, 16));
                if (((l >> 4) & 1) == 0)
                    M2b[(RT * 16 + (l & 15)) * M2LD + st * 2 + (l >> 5)] = f2bf(mcol);
            }
        }
        // group boundary: own DMA drained (vmcnt) + all waves done reading bstage[cur]
        __syncthreads();
    }

    // windowed max (6 consecutive h rows, start clip(h-3,0,18)) + fc_w-weighted sum
    float part = 0.f, wpart = 0.f;
    if (tid < HWSZ) {
        int h = tid >> 3;
        int st0 = h - 3; if (st0 < 0) st0 = 0; if (st0 > 18) st0 = 18;
        float v1 = -INFINITY, v2 = -INFINITY;
        #pragma unroll
        for (int i = 0; i < 6; ++i) {
            v1 = fmaxf(v1, bf2f(M1b[(st0 + i) * M1LD + tid]));
            v2 = fmaxf(v2, bf2f(M2b[tid * M2LD + st0 + i]));
        }
        float fw = fc_w[tid];
        part = fw * (v1 + v2);
        wpart = fw;
    }
    #pragma unroll
    for (int m = 1; m < 64; m <<= 1) {
        part  += __shfl_xor(part, m);
        wpart += __shfl_xor(wpart, m);
    }
    if (l == 0) { red[w] = part; wred[w] = wpart; }
    __syncthreads();

    if (tid == 0) {
        float total = red[0] + red[1] + red[2] + red[3] + red[4] + red[5];
        float Wsum  = wred[0] + wred[1] + wred[2] + wred[3] + wred[4] + wred[5];
        float k1 = bn_g[0] * rsqrtf(bn_v[0] + EPSV);
        float Y = k1 * total + 2.f * ((bn_b[0] - k1 * bn_m[0]) * Wsum + fc_b[0]);
        float kl = lbn_g[0] * rsqrtf(lbn_v[0] + EPSV);
        float Z = (Y - lbn_m[0]) * kl + lbn_b[0];
        out[bi] = 1.f / (1.f + expf(-Z));
    }
}

extern "C" void kernel_launch(void* const* d_in, const int* in_sizes, int n_in,
                              void* d_out, int out_size, void* d_ws, size_t ws_size,
                              hipStream_t stream)
{
    const float* prob  = (const float*)d_in[0];
    const float* gal   = (const float*)d_in[1];
    const float* se_w1 = (const float*)d_in[2];
    const float* se_w2 = (const float*)d_in[3];
    const float* sa_w  = (const float*)d_in[4];
    const float* sa_b  = (const float*)d_in[5];
    const float* bn_g  = (const float*)d_in[6];
    const float* bn_b  = (const float*)d_in[7];
    const float* bn_m  = (const float*)d_in[8];
    const float* bn_v  = (const float*)d_in[9];
    const float* fc_w  = (const float*)d_in[10];
    const float* fc_b  = (const float*)d_in[11];
    const float* lbn_g = (const float*)d_in[12];
    const float* lbn_b = (const float*)d_in[13];
    const float* lbn_m = (const float*)d_in[14];
    const float* lbn_v = (const float*)d_in[15];

    __hip_bfloat16* pf_t = (__hip_bfloat16*)d_ws;             // [32][192][128] bf16
    __hip_bfloat16* gf_t = pf_t + (size_t)32 * HWSZ * CC;     // [32][192][128] bf16
    float* ca_buf = (float*)(gf_t + (size_t)32 * HWSZ * CC);  // [64][128] f32
    float* sa_buf = ca_buf + 64 * CC;                         // [64][192] f32
    float* out = (float*)d_out;

    cbam_stats<<<64, 512, 0, stream>>>(prob, gal, se_w1, se_w2, sa_w, sa_b, ca_buf, sa_buf);
    cbam_apply<<<768, 256, 0, stream>>>(prob, gal, ca_buf, sa_buf, pf_t, gf_t);
    score_kernel<<<1024, 384, 0, stream>>>(pf_t, gf_t, bn_g, bn_b, bn_m, bn_v,
                                           fc_w, fc_b, lbn_g, lbn_b, lbn_m, lbn_v, out);
}